// Round 1
// baseline (396.290 us; speedup 1.0000x reference)
//
#include <hip/hip_runtime.h>
#include <stdint.h>

#define NNODES 10000
#define NEDGES 100000
#define DNODE 56
#define JTOT 1600

typedef __attribute__((ext_vector_type(8))) short short8;
typedef __attribute__((ext_vector_type(4))) float floatx4;

__device__ __forceinline__ unsigned short f2bf(float f) {
  unsigned u = __float_as_uint(f);
  u = u + 0x7fffu + ((u >> 16) & 1u);   // round-to-nearest-even
  return (unsigned short)(u >> 16);
}

__device__ __forceinline__ float mishf(float x) {
  // mish(x) = x * tanh(softplus(x)) = x * ((1+e^x)^2 - 1)/((1+e^x)^2 + 1)  (exact identity)
  float e = __expf(x);
  float z = 1.f + e; z = z * z;
  float t = (z - 1.f) / (z + 1.f);
  t = (x > 40.f) ? 1.f : t;             // overflow guard
  return x * t;
}

// ---- kernel 0: G[j][k] = bf16(fc2w[k][j])  (transpose + cast, 102400 elems)
__global__ __launch_bounds__(256) void k_tr(const float* __restrict__ fc2w,
                                            unsigned short* __restrict__ G) {
  int idx = blockIdx.x * 256 + threadIdx.x;
  if (idx >= 64 * JTOT) return;
  int j = idx >> 6, k = idx & 63;
  G[idx] = f2bf(fc2w[k * JTOT + j]);
}

// ---- kernel A: h[e][0:64] = mish(ea @ fc1 + b1), stored as bf16 bits
__global__ __launch_bounds__(256) void k_hidden(const float* __restrict__ ea,
                                                const float* __restrict__ fc1w,
                                                const float* __restrict__ fc1b,
                                                unsigned short* __restrict__ hb) {
  int e = blockIdx.x * 256 + threadIdx.x;
  if (e >= NEDGES) return;
  float a[64];
  const float4* row = (const float4*)(ea + (size_t)e * 64);
  #pragma unroll
  for (int i = 0; i < 16; i++) {
    float4 t = row[i];
    a[4*i] = t.x; a[4*i+1] = t.y; a[4*i+2] = t.z; a[4*i+3] = t.w;
  }
  for (int jb = 0; jb < 64; jb += 8) {
    float acc[8];
    #pragma unroll
    for (int i = 0; i < 8; i++) acc[i] = fc1b[jb + i];
    #pragma unroll
    for (int k = 0; k < 64; k++) {        // fc1w index is wave-uniform -> s_loads
      #pragma unroll
      for (int i = 0; i < 8; i++) acc[i] = fmaf(a[k], fc1w[k*64 + jb + i], acc[i]);
    }
    unsigned pk[4];
    #pragma unroll
    for (int i = 0; i < 4; i++) {
      unsigned lo = f2bf(mishf(acc[2*i]));
      unsigned hi = f2bf(mishf(acc[2*i+1]));
      pk[i] = lo | (hi << 16);
    }
    *(uint4*)(hb + (size_t)e*64 + jb) = make_uint4(pk[0], pk[1], pk[2], pk[3]);
  }
}

// ---- kernel B: fused  w = h@fc2+b2  (MFMA, C^T layout)  + tensor product + atomic scatter
// Wave owns 64 edges (4 n-tiles of 16). GEMM: C[j][e] = sum_k G[j][k] h[e][k] + b2[j].
// MFMA frags: A[m=lane&15][k=quad*8+i] = G row, B[k=quad*8+i][n=lane&15] = h row,
// C: col=lane&15 (edge), row=quad*4+reg (j).
__global__ __launch_bounds__(128, 2) void k_tp(
    const unsigned short* __restrict__ hb,
    const unsigned short* __restrict__ G,
    const float* __restrict__ fc2b,
    const int* __restrict__ eidx,
    const float* __restrict__ node_attr,
    const float* __restrict__ edge_sh,
    float* __restrict__ nsum,
    float* __restrict__ cnt) {
  __shared__ float b2s[JTOT];
  __shared__ float wls[2][64 * 64];   // per-wave coef tables: [u<32]=s, [32+u*3+c]=v, [56+u]=dot
  const int tid = threadIdx.x;
  const int wave = tid >> 6, lane = tid & 63;
  for (int i = tid; i < JTOT; i += 128) b2s[i] = fc2b[i];

  const int e0 = (blockIdx.x * 2 + wave) * 64;
  float* Wt = &wls[wave][0];
  {
    int e = e0 + lane;
    bool valid = e < NEDGES;
    int dst = valid ? eidx[NEDGES + e] : 0;
    float4 sh = valid ? *(const float4*)(edge_sh + 4*(size_t)e) : make_float4(0.f,0.f,0.f,0.f);
    const float* na = node_attr + (size_t)dst * DNODE;
    #pragma unroll
    for (int u = 0; u < 32; u += 4) {
      float4 t = *(const float4*)(na + u);
      Wt[(u+0)*64 + lane] = t.x;
      Wt[(u+1)*64 + lane] = t.y;
      Wt[(u+2)*64 + lane] = t.z;
      Wt[(u+3)*64 + lane] = t.w;
    }
    const float rs3 = 0.57735026918962576f;  // 1/sqrt(3)
    #pragma unroll
    for (int u = 0; u < 8; u++) {
      float v0 = na[32 + u*3 + 0];
      float v1 = na[32 + u*3 + 1];
      float v2 = na[32 + u*3 + 2];
      Wt[(32 + u*3 + 0)*64 + lane] = v0;
      Wt[(32 + u*3 + 1)*64 + lane] = v1;
      Wt[(32 + u*3 + 2)*64 + lane] = v2;
      Wt[(56 + u)*64 + lane] = (v0*sh.y + v1*sh.z + v2*sh.w) * rs3;   // dot (OOB: sh=0 -> 0)
    }
  }
  __syncthreads();

  const int col = lane & 15, rg = lane >> 4, rgh = rg >> 1;
  float sh0c[4], sh1c[4][3];
  int srcn[4]; bool vld[4];
  short8 bfrag[4][2];
  const short8 zfrag = {0,0,0,0,0,0,0,0};
  #pragma unroll
  for (int nt = 0; nt < 4; nt++) {
    int e = e0 + nt*16 + col;
    bool v = e < NEDGES; vld[nt] = v;
    if (v) {
      float4 sh = *(const float4*)(edge_sh + 4*(size_t)e);
      sh0c[nt] = sh.x; sh1c[nt][0] = sh.y; sh1c[nt][1] = sh.z; sh1c[nt][2] = sh.w;
      srcn[nt] = eidx[e];
      const unsigned short* hp = hb + (size_t)e * 64;
      bfrag[nt][0] = *(const short8*)(hp + rg*8);
      bfrag[nt][1] = *(const short8*)(hp + 32 + rg*8);
    } else {
      sh0c[nt] = 0.f; sh1c[nt][0] = sh1c[nt][1] = sh1c[nt][2] = 0.f;
      srcn[nt] = 0;
      bfrag[nt][0] = zfrag; bfrag[nt][1] = zfrag;
    }
  }

  float sacc[4][8], vacc[4][12];
  #pragma unroll
  for (int nt = 0; nt < 4; nt++) {
    #pragma unroll
    for (int i = 0; i < 8; i++) sacc[nt][i] = 0.f;
    #pragma unroll
    for (int i = 0; i < 12; i++) vacc[nt][i] = 0.f;
  }

  auto ldA = [&](int jt, short8& x0, short8& x1) {
    const unsigned short* p = G + (((jt<<4) + col) << 6) + rg*8;
    x0 = *(const short8*)p;
    x1 = *(const short8*)(p + 32);
  };
  auto mfma_tile = [&](int jt, short8 x0, short8 x1, floatx4* acc) {
    float4 b2v = *(const float4*)&b2s[jt*16 + rg*4];   // C init = bias b2[j]
    #pragma unroll
    for (int nt = 0; nt < 4; nt++) {
      floatx4 c = {b2v.x, b2v.y, b2v.z, b2v.w};
      c = __builtin_amdgcn_mfma_f32_16x16x32_bf16(x0, bfrag[nt][0], c, 0, 0, 0);
      c = __builtin_amdgcn_mfma_f32_16x16x32_bf16(x1, bfrag[nt][1], c, 0, 0, 0);
      acc[nt] = c;
    }
  };

  short8 a0, a1, n0, n1;
  ldA(0, a0, a1);

  // ---- w1 region: j in [0,1024): u = j>>5 (pair-uniform), wi = (jt&1)*16 + rg*4 + r
  #pragma unroll 1
  for (int jt = 0; jt < 64; jt += 2) {
    const int u = jt >> 1;
    float cf[4];
    #pragma unroll
    for (int nt = 0; nt < 4; nt++) cf[nt] = Wt[u*64 + nt*16 + col] * sh0c[nt];
    ldA(jt + 1, n0, n1);
    floatx4 acc[4];
    mfma_tile(jt, a0, a1, acc);
    #pragma unroll
    for (int nt = 0; nt < 4; nt++)
      #pragma unroll
      for (int r = 0; r < 4; r++) sacc[nt][r] = fmaf(cf[nt], acc[nt][r], sacc[nt][r]);
    ldA(jt + 2, a0, a1);
    mfma_tile(jt + 1, n0, n1, acc);
    #pragma unroll
    for (int nt = 0; nt < 4; nt++)
      #pragma unroll
      for (int r = 0; r < 4; r++) sacc[nt][4+r] = fmaf(cf[nt], acc[nt][r], sacc[nt][4+r]);
  }
  // ---- w2 region: j in [1024,1088): u = (jt-64)*2 + (rg>>1), wi = (rg&1)*4 + r, coef = v[u][c]*sh0
  #pragma unroll 1
  for (int jt = 64; jt < 68; jt++) {
    ldA(jt + 1, n0, n1);
    floatx4 acc[4];
    mfma_tile(jt, a0, a1, acc);
    const int u = (jt - 64)*2 + rgh;
    #pragma unroll
    for (int nt = 0; nt < 4; nt++)
      #pragma unroll
      for (int c3 = 0; c3 < 3; c3++) {
        float cfv = Wt[(32 + u*3 + c3)*64 + nt*16 + col] * sh0c[nt];
        #pragma unroll
        for (int r = 0; r < 4; r++) vacc[nt][c3*4+r] = fmaf(cfv, acc[nt][r], vacc[nt][c3*4+r]);
      }
    a0 = n0; a1 = n1;
  }
  // ---- w3 region: j in [1088,1344): u = (jt-68)*2 + (rg>>1), coef = s[u]*sh1[c]
  #pragma unroll 1
  for (int jt = 68; jt < 84; jt++) {
    ldA(jt + 1, n0, n1);
    floatx4 acc[4];
    mfma_tile(jt, a0, a1, acc);
    const int u = (jt - 68)*2 + rgh;
    #pragma unroll
    for (int nt = 0; nt < 4; nt++) {
      float sv = Wt[u*64 + nt*16 + col];
      #pragma unroll
      for (int c3 = 0; c3 < 3; c3++) {
        float cfv = sv * sh1c[nt][c3];
        #pragma unroll
        for (int r = 0; r < 4; r++) vacc[nt][c3*4+r] = fmaf(cfv, acc[nt][r], vacc[nt][c3*4+r]);
      }
    }
    a0 = n0; a1 = n1;
  }
  // ---- w4 region: j in [1344,1600): u = (jt-84)>>1, coef = dot[u], same out_s slots as w1
  #pragma unroll 1
  for (int jt = 84; jt < 100; jt += 2) {
    const int u = (jt - 84) >> 1;
    float cf[4];
    #pragma unroll
    for (int nt = 0; nt < 4; nt++) cf[nt] = Wt[(56 + u)*64 + nt*16 + col];
    ldA(jt + 1, n0, n1);
    floatx4 acc[4];
    mfma_tile(jt, a0, a1, acc);
    #pragma unroll
    for (int nt = 0; nt < 4; nt++)
      #pragma unroll
      for (int r = 0; r < 4; r++) sacc[nt][r] = fmaf(cf[nt], acc[nt][r], sacc[nt][r]);
    ldA(jt + 2 < 100 ? jt + 2 : 99, a0, a1);
    mfma_tile(jt + 1, n0, n1, acc);
    #pragma unroll
    for (int nt = 0; nt < 4; nt++)
      #pragma unroll
      for (int r = 0; r < 4; r++) sacc[nt][4+r] = fmaf(cf[nt], acc[nt][r], sacc[nt][4+r]);
  }

  // ---- epilogue: scale by a=1/sqrt(40), scatter-add by edge_src
  const float ascale = 0.15811388300841897f;
  #pragma unroll
  for (int nt = 0; nt < 4; nt++) {
    int base = srcn[nt] * DNODE;
    if (vld[nt]) {
      #pragma unroll
      for (int p = 0; p < 2; p++)
        #pragma unroll
        for (int r = 0; r < 4; r++)
          atomicAdd(&nsum[base + p*16 + rg*4 + r], ascale * sacc[nt][p*4+r]);
    }
    #pragma unroll
    for (int c3 = 0; c3 < 3; c3++)
      #pragma unroll
      for (int r = 0; r < 4; r++) {
        float tot = vacc[nt][c3*4+r] + __shfl_xor(vacc[nt][c3*4+r], 32);
        if ((rg < 2) && vld[nt])
          atomicAdd(&nsum[base + 32 + ((rg&1)*4 + r)*3 + c3], ascale * tot);
      }
    if (rg == 0 && vld[nt]) atomicAdd(&cnt[srcn[nt]], 1.0f);
  }
}

// ---- kernel C1: out_pre = nsum/max(cnt,1) + node_attr (in-place into nsum) + BN stat partials
__global__ __launch_bounds__(256) void k_agg(float* __restrict__ nsum,
                                             const float* __restrict__ cnt,
                                             const float* __restrict__ node_attr,
                                             float* __restrict__ stats) {
  __shared__ float part[72];
  int t = threadIdx.x;
  if (t < 72) part[t] = 0.f;
  __syncthreads();
  int idx = blockIdx.x * 256 + t;
  if (idx < NNODES * DNODE) {
    int n = idx / DNODE;
    int d = idx - n * DNODE;
    float c = cnt[n];
    c = c > 1.f ? c : 1.f;
    float val = nsum[idx] / c + node_attr[idx];
    nsum[idx] = val;
    if (d < 32) {
      atomicAdd(&part[d], val);
      atomicAdd(&part[32 + d], val * val);
    } else {
      int wi = (d - 32) / 3;
      atomicAdd(&part[64 + wi], val * val);
    }
  }
  __syncthreads();
  if (t < 72) atomicAdd(&stats[t], part[t]);
}

// ---- kernel C2: batch norm -> d_out
__global__ __launch_bounds__(256) void k_norm(const float* __restrict__ pre,
                                              const float* __restrict__ stats,
                                              const float* __restrict__ gs,
                                              const float* __restrict__ bs,
                                              const float* __restrict__ gv,
                                              float* __restrict__ out) {
  int idx = blockIdx.x * 256 + threadIdx.x;
  if (idx >= NNODES * DNODE) return;
  int n = idx / DNODE;
  int d = idx - n * DNODE;
  float val = pre[idx];
  const float invN = 1.f / (float)NNODES;
  float res;
  if (d < 32) {
    float mu = stats[d] * invN;
    float var = stats[32 + d] * invN - mu * mu;
    res = (val - mu) * rsqrtf(var + 1e-4f) * gs[d] + bs[d];
  } else {
    int wi = (d - 32) / 3;
    float vn = stats[64 + wi] * (invN / 3.f);
    res = val * rsqrtf(vn + 1e-4f) * gv[wi];
  }
  out[idx] = res;
}

extern "C" void kernel_launch(void* const* d_in, const int* in_sizes, int n_in,
                              void* d_out, int out_size, void* d_ws, size_t ws_size,
                              hipStream_t stream) {
  const float* node_attr = (const float*)d_in[0];
  const int*   eidx      = (const int*)d_in[1];
  const float* edge_attr = (const float*)d_in[2];
  const float* edge_sh   = (const float*)d_in[3];
  const float* fc1w      = (const float*)d_in[4];
  const float* fc1b      = (const float*)d_in[5];
  const float* fc2w      = (const float*)d_in[6];
  const float* fc2b      = (const float*)d_in[7];
  const float* gs        = (const float*)d_in[8];
  const float* bs        = (const float*)d_in[9];
  const float* gv        = (const float*)d_in[10];

  float* ws = (float*)d_ws;
  float* nsum  = ws;                    // 560000 floats (also out_pre, in-place)
  float* cnt   = ws + 560000;           // 10000
  float* stats = ws + 570000;           // 72 (padded to 570112)
  unsigned short* G  = (unsigned short*)(ws + 570112);   // 102400 bf16
  unsigned short* hb = (unsigned short*)(ws + 621312);   // 6.4M bf16

  hipMemsetAsync(nsum, 0, (size_t)570072 * 4, stream);   // nsum + cnt + stats
  k_tr<<<400, 256, 0, stream>>>(fc2w, G);
  k_hidden<<<(NEDGES + 255) / 256, 256, 0, stream>>>(edge_attr, fc1w, fc1b, hb);
  k_tp<<<782, 128, 0, stream>>>(hb, G, fc2b, eidx, node_attr, edge_sh, nsum, cnt);
  k_agg<<<(NNODES * DNODE + 255) / 256, 256, 0, stream>>>(nsum, cnt, node_attr, stats);
  k_norm<<<(NNODES * DNODE + 255) / 256, 256, 0, stream>>>(nsum, stats, gs, bs, gv, (float*)d_out);
}

// Round 2
// 252.980 us; speedup vs baseline: 1.5665x; 1.5665x over previous
//
#include <hip/hip_runtime.h>
#include <stdint.h>

#define NNODES 10000
#define NEDGES 100000
#define DNODE 56
#define JTOT 1600

typedef __attribute__((ext_vector_type(8))) short short8;
typedef __attribute__((ext_vector_type(4))) float floatx4;

__device__ __forceinline__ unsigned short f2bf(float f) {
  unsigned u = __float_as_uint(f);
  u = u + 0x7fffu + ((u >> 16) & 1u);   // round-to-nearest-even
  return (unsigned short)(u >> 16);
}

__device__ __forceinline__ float mishf(float x) {
  float e = __expf(x);
  float z = 1.f + e; z = z * z;
  float t = (z - 1.f) / (z + 1.f);
  t = (x > 40.f) ? 1.f : t;
  return x * t;
}

// ---- kernel 0: G[j][k] = bf16(fc2w[k][j])
__global__ __launch_bounds__(256) void k_tr(const float* __restrict__ fc2w,
                                            unsigned short* __restrict__ G) {
  int idx = blockIdx.x * 256 + threadIdx.x;
  if (idx >= 64 * JTOT) return;
  int j = idx >> 6, k = idx & 63;
  G[idx] = f2bf(fc2w[k * JTOT + j]);
}

// ---- kernel A: h[e][0:64] = mish(ea @ fc1 + b1) as bf16
__global__ __launch_bounds__(256) void k_hidden(const float* __restrict__ ea,
                                                const float* __restrict__ fc1w,
                                                const float* __restrict__ fc1b,
                                                unsigned short* __restrict__ hb) {
  int e = blockIdx.x * 256 + threadIdx.x;
  if (e >= NEDGES) return;
  float a[64];
  const float4* row = (const float4*)(ea + (size_t)e * 64);
  #pragma unroll
  for (int i = 0; i < 16; i++) {
    float4 t = row[i];
    a[4*i] = t.x; a[4*i+1] = t.y; a[4*i+2] = t.z; a[4*i+3] = t.w;
  }
  for (int jb = 0; jb < 64; jb += 8) {
    float acc[8];
    #pragma unroll
    for (int i = 0; i < 8; i++) acc[i] = fc1b[jb + i];
    #pragma unroll
    for (int k = 0; k < 64; k++) {
      #pragma unroll
      for (int i = 0; i < 8; i++) acc[i] = fmaf(a[k], fc1w[k*64 + jb + i], acc[i]);
    }
    unsigned pk[4];
    #pragma unroll
    for (int i = 0; i < 4; i++) {
      unsigned lo = f2bf(mishf(acc[2*i]));
      unsigned hi = f2bf(mishf(acc[2*i+1]));
      pk[i] = lo | (hi << 16);
    }
    *(uint4*)(hb + (size_t)e*64 + jb) = make_uint4(pk[0], pk[1], pk[2], pk[3]);
  }
}

// ---- CSR build: histogram, scan, permutation
__global__ __launch_bounds__(256) void k_hist(const int* __restrict__ eidx,
                                              int* __restrict__ cntn) {
  int e = blockIdx.x * 256 + threadIdx.x;
  if (e >= NEDGES) return;
  atomicAdd(&cntn[eidx[e]], 1);
}

__global__ __launch_bounds__(1024) void k_scan(const int* __restrict__ cntn,
                                               int* __restrict__ offs,
                                               int* __restrict__ cursor) {
  __shared__ int ts[1024];
  int t = threadIdx.x;
  int base = t * 10;
  int loc[10]; int s = 0;
  #pragma unroll
  for (int i = 0; i < 10; i++) {
    int idx = base + i;
    int v = (idx < NNODES) ? cntn[idx] : 0;
    loc[i] = s; s += v;
  }
  ts[t] = s;
  __syncthreads();
  for (int off = 1; off < 1024; off <<= 1) {
    int v = (t >= off) ? ts[t - off] : 0;
    __syncthreads();
    ts[t] += v;
    __syncthreads();
  }
  int excl = (t == 0) ? 0 : ts[t - 1];
  #pragma unroll
  for (int i = 0; i < 10; i++) {
    int idx = base + i;
    if (idx < NNODES) { int o = excl + loc[i]; offs[idx] = o; cursor[idx] = o; }
  }
  if (t == 1023) offs[NNODES] = ts[1023];
}

__global__ __launch_bounds__(256) void k_perm(const int* __restrict__ eidx,
                                              int* __restrict__ cursor,
                                              int* __restrict__ perm) {
  int e = blockIdx.x * 256 + threadIdx.x;
  if (e >= NEDGES) return;
  int s = eidx[e];
  int pos = atomicAdd(&cursor[s], 1);
  perm[pos] = e;
}

// ---- kernel B: fused w = h@fc2+b2 (MFMA, C^T layout) + tensor product -> tp[e][56]
__global__ __launch_bounds__(128, 2) void k_tp(
    const unsigned short* __restrict__ hb,
    const unsigned short* __restrict__ G,
    const float* __restrict__ fc2b,
    const int* __restrict__ eidx,
    const float* __restrict__ node_attr,
    const float* __restrict__ edge_sh,
    float* __restrict__ tp) {
  __shared__ float b2s[JTOT];
  __shared__ float wls[2][64 * 64];   // coef tables, reused as transpose buffer in epilogue
  const int tid = threadIdx.x;
  const int wave = tid >> 6, lane = tid & 63;
  for (int i = tid; i < JTOT; i += 128) b2s[i] = fc2b[i];

  const int e0 = (blockIdx.x * 2 + wave) * 64;
  float* Wt = &wls[wave][0];
  {
    int e = e0 + lane;
    bool valid = e < NEDGES;
    int dst = valid ? eidx[NEDGES + e] : 0;
    float4 sh = valid ? *(const float4*)(edge_sh + 4*(size_t)e) : make_float4(0.f,0.f,0.f,0.f);
    const float* na = node_attr + (size_t)dst * DNODE;
    #pragma unroll
    for (int u = 0; u < 32; u += 4) {
      float4 t = *(const float4*)(na + u);
      Wt[(u+0)*64 + lane] = t.x;
      Wt[(u+1)*64 + lane] = t.y;
      Wt[(u+2)*64 + lane] = t.z;
      Wt[(u+3)*64 + lane] = t.w;
    }
    const float rs3 = 0.57735026918962576f;
    #pragma unroll
    for (int u = 0; u < 8; u++) {
      float v0 = na[32 + u*3 + 0];
      float v1 = na[32 + u*3 + 1];
      float v2 = na[32 + u*3 + 2];
      Wt[(32 + u*3 + 0)*64 + lane] = v0;
      Wt[(32 + u*3 + 1)*64 + lane] = v1;
      Wt[(32 + u*3 + 2)*64 + lane] = v2;
      Wt[(56 + u)*64 + lane] = (v0*sh.y + v1*sh.z + v2*sh.w) * rs3;
    }
  }
  __syncthreads();

  const int col = lane & 15, rg = lane >> 4, rgh = rg >> 1;
  float sh0c[4], sh1c[4][3];
  bool vld[4];
  short8 bfrag[4][2];
  const short8 zfrag = {0,0,0,0,0,0,0,0};
  #pragma unroll
  for (int nt = 0; nt < 4; nt++) {
    int e = e0 + nt*16 + col;
    bool v = e < NEDGES; vld[nt] = v;
    if (v) {
      float4 sh = *(const float4*)(edge_sh + 4*(size_t)e);
      sh0c[nt] = sh.x; sh1c[nt][0] = sh.y; sh1c[nt][1] = sh.z; sh1c[nt][2] = sh.w;
      const unsigned short* hp = hb + (size_t)e * 64;
      bfrag[nt][0] = *(const short8*)(hp + rg*8);
      bfrag[nt][1] = *(const short8*)(hp + 32 + rg*8);
    } else {
      sh0c[nt] = 0.f; sh1c[nt][0] = sh1c[nt][1] = sh1c[nt][2] = 0.f;
      bfrag[nt][0] = zfrag; bfrag[nt][1] = zfrag;
    }
  }

  float sacc[4][8], vacc[4][12];
  #pragma unroll
  for (int nt = 0; nt < 4; nt++) {
    #pragma unroll
    for (int i = 0; i < 8; i++) sacc[nt][i] = 0.f;
    #pragma unroll
    for (int i = 0; i < 12; i++) vacc[nt][i] = 0.f;
  }

  auto ldA = [&](int jt, short8& x0, short8& x1) {
    const unsigned short* p = G + (((jt<<4) + col) << 6) + rg*8;
    x0 = *(const short8*)p;
    x1 = *(const short8*)(p + 32);
  };
  auto ldB2 = [&](int jt) -> float4 {
    return *(const float4*)&b2s[jt*16 + rg*4];
  };
  auto mfma_tile = [&](short8 x0, short8 x1, float4 b2v, floatx4* acc) {
    #pragma unroll
    for (int nt = 0; nt < 4; nt++) {
      floatx4 c = {b2v.x, b2v.y, b2v.z, b2v.w};
      c = __builtin_amdgcn_mfma_f32_16x16x32_bf16(x0, bfrag[nt][0], c, 0, 0, 0);
      c = __builtin_amdgcn_mfma_f32_16x16x32_bf16(x1, bfrag[nt][1], c, 0, 0, 0);
      acc[nt] = c;
    }
  };

  short8 a0, a1, n0, n1;
  float4 bc, bn;
  ldA(0, a0, a1); bc = ldB2(0);

  // ---- w1: j in [0,1024)
  #pragma unroll 1
  for (int jt = 0; jt < 64; jt += 2) {
    const int u = jt >> 1;
    float cf[4];
    #pragma unroll
    for (int nt = 0; nt < 4; nt++) cf[nt] = Wt[u*64 + nt*16 + col] * sh0c[nt];
    ldA(jt + 1, n0, n1); bn = ldB2(jt + 1);
    floatx4 acc[4];
    mfma_tile(a0, a1, bc, acc);
    #pragma unroll
    for (int nt = 0; nt < 4; nt++)
      #pragma unroll
      for (int r = 0; r < 4; r++) sacc[nt][r] = fmaf(cf[nt], acc[nt][r], sacc[nt][r]);
    ldA(jt + 2, a0, a1); bc = ldB2(jt + 2);
    mfma_tile(n0, n1, bn, acc);
    #pragma unroll
    for (int nt = 0; nt < 4; nt++)
      #pragma unroll
      for (int r = 0; r < 4; r++) sacc[nt][4+r] = fmaf(cf[nt], acc[nt][r], sacc[nt][4+r]);
  }
  // ---- w2: j in [1024,1088)
  #pragma unroll 1
  for (int jt = 64; jt < 68; jt++) {
    ldA(jt + 1, n0, n1); bn = ldB2(jt + 1);
    floatx4 acc[4];
    mfma_tile(a0, a1, bc, acc);
    const int u = (jt - 64)*2 + rgh;
    #pragma unroll
    for (int nt = 0; nt < 4; nt++)
      #pragma unroll
      for (int c3 = 0; c3 < 3; c3++) {
        float cfv = Wt[(32 + u*3 + c3)*64 + nt*16 + col] * sh0c[nt];
        #pragma unroll
        for (int r = 0; r < 4; r++) vacc[nt][c3*4+r] = fmaf(cfv, acc[nt][r], vacc[nt][c3*4+r]);
      }
    a0 = n0; a1 = n1; bc = bn;
  }
  // ---- w3: j in [1088,1344)
  #pragma unroll 1
  for (int jt = 68; jt < 84; jt++) {
    ldA(jt + 1, n0, n1); bn = ldB2(jt + 1);
    floatx4 acc[4];
    mfma_tile(a0, a1, bc, acc);
    const int u = (jt - 68)*2 + rgh;
    #pragma unroll
    for (int nt = 0; nt < 4; nt++) {
      float sv = Wt[u*64 + nt*16 + col];
      #pragma unroll
      for (int c3 = 0; c3 < 3; c3++) {
        float cfv = sv * sh1c[nt][c3];
        #pragma unroll
        for (int r = 0; r < 4; r++) vacc[nt][c3*4+r] = fmaf(cfv, acc[nt][r], vacc[nt][c3*4+r]);
      }
    }
    a0 = n0; a1 = n1; bc = bn;
  }
  // ---- w4: j in [1344,1600)
  #pragma unroll 1
  for (int jt = 84; jt < 100; jt += 2) {
    const int u = (jt - 84) >> 1;
    float cf[4];
    #pragma unroll
    for (int nt = 0; nt < 4; nt++) cf[nt] = Wt[(56 + u)*64 + nt*16 + col];
    ldA(jt + 1, n0, n1); bn = ldB2(jt + 1);
    floatx4 acc[4];
    mfma_tile(a0, a1, bc, acc);
    #pragma unroll
    for (int nt = 0; nt < 4; nt++)
      #pragma unroll
      for (int r = 0; r < 4; r++) sacc[nt][r] = fmaf(cf[nt], acc[nt][r], sacc[nt][r]);
    int pj = (jt + 2 < 100) ? jt + 2 : 99;
    ldA(pj, a0, a1); bc = ldB2(pj);
    mfma_tile(n0, n1, bn, acc);
    #pragma unroll
    for (int nt = 0; nt < 4; nt++)
      #pragma unroll
      for (int r = 0; r < 4; r++) sacc[nt][4+r] = fmaf(cf[nt], acc[nt][r], sacc[nt][4+r]);
  }

  // ---- epilogue: scale, reduce vector halves, transpose through LDS, coalesced row store
  const float ascale = 0.15811388300841897f;   // 1/sqrt(40)
  __syncthreads();   // all coef-table reads done before reuse
  #pragma unroll
  for (int nt = 0; nt < 4; nt++) {
    int el = nt*16 + col;
    #pragma unroll
    for (int p = 0; p < 2; p++)
      #pragma unroll
      for (int r = 0; r < 4; r++)
        wls[wave][el*64 + p*16 + rg*4 + r] = ascale * sacc[nt][p*4+r];
    #pragma unroll
    for (int c3 = 0; c3 < 3; c3++)
      #pragma unroll
      for (int r = 0; r < 4; r++) {
        float tot = vacc[nt][c3*4+r] + __shfl_xor(vacc[nt][c3*4+r], 32);
        if (rg < 2)
          wls[wave][el*64 + 32 + ((rg&1)*4 + r)*3 + c3] = ascale * tot;
      }
  }
  __syncthreads();
  #pragma unroll
  for (int it = 0; it < 14; it++) {
    int flat = it*64 + lane;           // 0..895 float4 slots (64 rows x 14)
    int el = flat / 14, fq = flat - el*14;
    int e = e0 + el;
    if (e < NEDGES)
      *(float4*)(tp + (size_t)e*DNODE + fq*4) = *(float4*)&wls[wave][el*64 + fq*4];
  }
}

// ---- kernel C1: per-node mean + residual + BN stat partials (CSR gather)
__global__ __launch_bounds__(256) void k_gather(const float* __restrict__ tp,
                                                const int* __restrict__ offs,
                                                const int* __restrict__ perm,
                                                const float* __restrict__ node_attr,
                                                float* __restrict__ pre,
                                                float* __restrict__ stats) {
  __shared__ float redS[4*64], redQ[4*64];
  int t = threadIdx.x, wave = t >> 6, lane = t & 63;
  int gw = blockIdx.x * 4 + wave, W = gridDim.x * 4;
  int off = (lane < DNODE) ? lane : 0;
  float ssum = 0.f, ssq = 0.f;
  for (int n = gw; n < NNODES; n += W) {
    int beg = offs[n], end = offs[n+1];
    float acc = 0.f;
    int i = beg;
    for (; i + 4 <= end; i += 4) {
      int e0 = perm[i], e1 = perm[i+1], e2 = perm[i+2], e3 = perm[i+3];
      float v0 = tp[(size_t)e0*DNODE + off];
      float v1 = tp[(size_t)e1*DNODE + off];
      float v2 = tp[(size_t)e2*DNODE + off];
      float v3 = tp[(size_t)e3*DNODE + off];
      acc += (v0 + v1) + (v2 + v3);
    }
    for (; i < end; i++) acc += tp[(size_t)perm[i]*DNODE + off];
    int c = end - beg; if (c < 1) c = 1;
    float m = acc / (float)c + node_attr[(size_t)n*DNODE + off];
    if (lane < DNODE) pre[(size_t)n*DNODE + lane] = m;
    if (lane < DNODE) { ssum += m; ssq += m*m; }
  }
  redS[wave*64 + lane] = ssum;
  redQ[wave*64 + lane] = ssq;
  __syncthreads();
  if (wave == 0 && lane < DNODE) {
    float a = redS[lane] + redS[64+lane] + redS[128+lane] + redS[192+lane];
    float b = redQ[lane] + redQ[64+lane] + redQ[128+lane] + redQ[192+lane];
    atomicAdd(&stats[lane], a);
    atomicAdd(&stats[DNODE + lane], b);
  }
}

// ---- kernel C2: batch norm -> d_out
__global__ __launch_bounds__(256) void k_norm(const float* __restrict__ pre,
                                              const float* __restrict__ stats,
                                              const float* __restrict__ gs,
                                              const float* __restrict__ bs,
                                              const float* __restrict__ gv,
                                              float* __restrict__ out) {
  int idx = blockIdx.x * 256 + threadIdx.x;
  if (idx >= NNODES * DNODE) return;
  int n = idx / DNODE;
  int d = idx - n * DNODE;
  float val = pre[idx];
  const float invN = 1.f / (float)NNODES;
  float res;
  if (d < 32) {
    float mu = stats[d] * invN;
    float var = stats[DNODE + d] * invN - mu * mu;
    res = (val - mu) * rsqrtf(var + 1e-4f) * gs[d] + bs[d];
  } else {
    int wi = (d - 32) / 3;
    float vn = (stats[DNODE + 32 + wi*3] + stats[DNODE + 32 + wi*3 + 1] +
                stats[DNODE + 32 + wi*3 + 2]) * (invN / 3.f);
    res = val * rsqrtf(vn + 1e-4f) * gv[wi];
  }
  out[idx] = res;
}

extern "C" void kernel_launch(void* const* d_in, const int* in_sizes, int n_in,
                              void* d_out, int out_size, void* d_ws, size_t ws_size,
                              hipStream_t stream) {
  const float* node_attr = (const float*)d_in[0];
  const int*   eidx      = (const int*)d_in[1];
  const float* edge_attr = (const float*)d_in[2];
  const float* edge_sh   = (const float*)d_in[3];
  const float* fc1w      = (const float*)d_in[4];
  const float* fc1b      = (const float*)d_in[5];
  const float* fc2w      = (const float*)d_in[6];
  const float* fc2b      = (const float*)d_in[7];
  const float* gs        = (const float*)d_in[8];
  const float* bs        = (const float*)d_in[9];
  const float* gv        = (const float*)d_in[10];

  float* ws = (float*)d_ws;
  // layout (float offsets):
  float* tp    = ws;                               // 100032*56 = 5,601,792
  float* pre   = ws + 5601792;                     // 560,000
  float* stats = ws + 6161792;                     // 112 (pad to 128)
  int*   cntn  = (int*)(ws + 6161920);             // 10,000
  int*   offs  = (int*)(ws + 6171920);             // 10,001 (pad to 10,008)
  int*   cursor= (int*)(ws + 6181928);             // 10,000
  int*   perm  = (int*)(ws + 6191928);             // 100,000 (pad to 100,040)
  unsigned short* G  = (unsigned short*)(ws + 6291968);   // 102,400 bf16
  unsigned short* hb = (unsigned short*)(ws + 6343168);   // 6,400,000 bf16
  // total ≈ 9,543,168 floats = 38.2 MB

  // zero: stats + pad + cntn  (40.5 KB)
  hipMemsetAsync(stats, 0, (size_t)(6171920 - 6161792) * 4, stream);
  k_tr<<<400, 256, 0, stream>>>(fc2w, G);
  k_hidden<<<(NEDGES + 255) / 256, 256, 0, stream>>>(edge_attr, fc1w, fc1b, hb);
  k_hist<<<(NEDGES + 255) / 256, 256, 0, stream>>>(eidx, cntn);
  k_scan<<<1, 1024, 0, stream>>>(cntn, offs, cursor);
  k_perm<<<(NEDGES + 255) / 256, 256, 0, stream>>>(eidx, cursor, perm);
  k_tp<<<782, 128, 0, stream>>>(hb, G, fc2b, eidx, node_attr, edge_sh, tp);
  k_gather<<<256, 256, 0, stream>>>(tp, offs, perm, node_attr, pre, stats);
  k_norm<<<(NNODES * DNODE + 255) / 256, 256, 0, stream>>>(pre, stats, gs, bs, gv, (float*)d_out);
}

// Round 3
// 239.768 us; speedup vs baseline: 1.6528x; 1.0551x over previous
//
#include <hip/hip_runtime.h>
#include <stdint.h>

#define NNODES 10000
#define NEDGES 100000
#define DNODE 56
#define JTOT 1600

typedef __attribute__((ext_vector_type(8))) short short8;
typedef __attribute__((ext_vector_type(4))) float floatx4;

__device__ __forceinline__ unsigned short f2bf(float f) {
  unsigned u = __float_as_uint(f);
  u = u + 0x7fffu + ((u >> 16) & 1u);
  return (unsigned short)(u >> 16);
}

__device__ __forceinline__ float mishf(float x) {
  float e = __expf(x);
  float z = 1.f + e; z = z * z;
  float t = (z - 1.f) / (z + 1.f);
  t = (x > 40.f) ? 1.f : t;
  return x * t;
}

// ---- G[j][k] = bf16(fc2w[k][j])
__global__ __launch_bounds__(256) void k_tr(const float* __restrict__ fc2w,
                                            unsigned short* __restrict__ G) {
  int idx = blockIdx.x * 256 + threadIdx.x;
  if (idx >= 64 * JTOT) return;
  int j = idx >> 6, k = idx & 63;
  G[idx] = f2bf(fc2w[k * JTOT + j]);
}

// ---- h = mish(ea @ fc1 + b1) as bf16; fused edge_src histogram
__global__ __launch_bounds__(256) void k_hidden(const float* __restrict__ ea,
                                                const float* __restrict__ fc1w,
                                                const float* __restrict__ fc1b,
                                                const int* __restrict__ eidx,
                                                int* __restrict__ cntn,
                                                unsigned short* __restrict__ hb) {
  int e = blockIdx.x * 256 + threadIdx.x;
  if (e >= NEDGES) return;
  atomicAdd(&cntn[eidx[e]], 1);
  float a[64];
  const float4* row = (const float4*)(ea + (size_t)e * 64);
  #pragma unroll
  for (int i = 0; i < 16; i++) {
    float4 t = row[i];
    a[4*i] = t.x; a[4*i+1] = t.y; a[4*i+2] = t.z; a[4*i+3] = t.w;
  }
  for (int jb = 0; jb < 64; jb += 8) {
    float acc[8];
    #pragma unroll
    for (int i = 0; i < 8; i++) acc[i] = fc1b[jb + i];
    #pragma unroll
    for (int k = 0; k < 64; k++) {
      #pragma unroll
      for (int i = 0; i < 8; i++) acc[i] = fmaf(a[k], fc1w[k*64 + jb + i], acc[i]);
    }
    unsigned pk[4];
    #pragma unroll
    for (int i = 0; i < 4; i++) {
      unsigned lo = f2bf(mishf(acc[2*i]));
      unsigned hi = f2bf(mishf(acc[2*i+1]));
      pk[i] = lo | (hi << 16);
    }
    *(uint4*)(hb + (size_t)e*64 + jb) = make_uint4(pk[0], pk[1], pk[2], pk[3]);
  }
}

__global__ __launch_bounds__(1024) void k_scan(const int* __restrict__ cntn,
                                               int* __restrict__ offs,
                                               int* __restrict__ cursor) {
  __shared__ int ts[1024];
  int t = threadIdx.x;
  int base = t * 10;
  int loc[10]; int s = 0;
  #pragma unroll
  for (int i = 0; i < 10; i++) {
    int idx = base + i;
    int v = (idx < NNODES) ? cntn[idx] : 0;
    loc[i] = s; s += v;
  }
  ts[t] = s;
  __syncthreads();
  for (int off = 1; off < 1024; off <<= 1) {
    int v = (t >= off) ? ts[t - off] : 0;
    __syncthreads();
    ts[t] += v;
    __syncthreads();
  }
  int excl = (t == 0) ? 0 : ts[t - 1];
  #pragma unroll
  for (int i = 0; i < 10; i++) {
    int idx = base + i;
    if (idx < NNODES) { int o = excl + loc[i]; offs[idx] = o; cursor[idx] = o; }
  }
  if (t == 1023) offs[NNODES] = ts[1023];
}

// ---- pos[e] = CSR slot of edge e
__global__ __launch_bounds__(256) void k_perm(const int* __restrict__ eidx,
                                              int* __restrict__ cursor,
                                              int* __restrict__ pos) {
  int e = blockIdx.x * 256 + threadIdx.x;
  if (e >= NEDGES) return;
  pos[e] = atomicAdd(&cursor[eidx[e]], 1);
}

// ---- fused w = h@fc2+b2 (MFMA C^T) + tensor product -> tp[pos[e]][56]
// Block: 256 thr = 4 waves = 2 edge-groups (eg) x 2 j-halves (jh).
// Each (eg,jh) wave: 64 edges x 25 alternating jt-pairs (50 of 100 tiles).
__global__ __launch_bounds__(256, 2) void k_tp(
    const unsigned short* __restrict__ hb,
    const unsigned short* __restrict__ G,
    const float* __restrict__ fc2b,
    const int* __restrict__ eidx,
    const float* __restrict__ node_attr,
    const float* __restrict__ edge_sh,
    const int* __restrict__ pos,
    float* __restrict__ tp) {
  __shared__ float b2s[JTOT];
  __shared__ float X[2][64 * 64];     // per-eg: coef table -> partial exchange -> transpose buf
  __shared__ int pos_s[2][64];
  const int tid = threadIdx.x;
  const int wave = tid >> 6, lane = tid & 63;
  const int eg = wave & 1, jh = wave >> 1;
  for (int i = tid; i < JTOT; i += 256) b2s[i] = fc2b[i];

  const int e0 = (blockIdx.x * 2 + eg) * 64;
  float* Wt = &X[eg][0];
  if (jh == 0) {      // stage coef table (lane = edge)
    int e = e0 + lane;
    bool valid = e < NEDGES;
    int dst = valid ? eidx[NEDGES + e] : 0;
    pos_s[eg][lane] = valid ? pos[e] : 0;
    float4 sh = valid ? *(const float4*)(edge_sh + 4*(size_t)e) : make_float4(0.f,0.f,0.f,0.f);
    const float* na = node_attr + (size_t)dst * DNODE;
    #pragma unroll
    for (int u = 0; u < 32; u += 4) {
      float4 t = *(const float4*)(na + u);
      Wt[(u+0)*64 + lane] = t.x;
      Wt[(u+1)*64 + lane] = t.y;
      Wt[(u+2)*64 + lane] = t.z;
      Wt[(u+3)*64 + lane] = t.w;
    }
    const float rs3 = 0.57735026918962576f;
    #pragma unroll
    for (int u = 0; u < 8; u++) {
      float v0 = na[32 + u*3 + 0];
      float v1 = na[32 + u*3 + 1];
      float v2 = na[32 + u*3 + 2];
      Wt[(32 + u*3 + 0)*64 + lane] = v0;
      Wt[(32 + u*3 + 1)*64 + lane] = v1;
      Wt[(32 + u*3 + 2)*64 + lane] = v2;
      Wt[(56 + u)*64 + lane] = (v0*sh.y + v1*sh.z + v2*sh.w) * rs3;
    }
  }
  __syncthreads();

  const int col = lane & 15, rg = lane >> 4, rgh = rg >> 1;
  float sh0c[4], sh1c[4][3];
  bool vld[4];
  short8 bfrag[4][2];
  const short8 zfrag = {0,0,0,0,0,0,0,0};
  #pragma unroll
  for (int nt = 0; nt < 4; nt++) {
    int e = e0 + nt*16 + col;
    bool v = e < NEDGES; vld[nt] = v;
    if (v) {
      float4 sh = *(const float4*)(edge_sh + 4*(size_t)e);
      sh0c[nt] = sh.x; sh1c[nt][0] = sh.y; sh1c[nt][1] = sh.z; sh1c[nt][2] = sh.w;
      const unsigned short* hp = hb + (size_t)e * 64;
      bfrag[nt][0] = *(const short8*)(hp + rg*8);
      bfrag[nt][1] = *(const short8*)(hp + 32 + rg*8);
    } else {
      sh0c[nt] = 0.f; sh1c[nt][0] = sh1c[nt][1] = sh1c[nt][2] = 0.f;
      bfrag[nt][0] = zfrag; bfrag[nt][1] = zfrag;
    }
  }

  float sacc[4][8], vacc[4][12];
  #pragma unroll
  for (int nt = 0; nt < 4; nt++) {
    #pragma unroll
    for (int i = 0; i < 8; i++) sacc[nt][i] = 0.f;
    #pragma unroll
    for (int i = 0; i < 12; i++) vacc[nt][i] = 0.f;
  }

  auto ldpair = [&](int p, short8& f0, short8& f1, short8& f2, short8& f3) {
    const unsigned short* q0 = G + ((((2*p) << 4) + col) << 6) + rg*8;
    f0 = *(const short8*)q0;
    f1 = *(const short8*)(q0 + 32);
    const unsigned short* q1 = q0 + 1024;     // jt+1
    f2 = *(const short8*)q1;
    f3 = *(const short8*)(q1 + 32);
  };

  short8 cur0, cur1, cur2, cur3, nx0, nx1, nx2, nx3;
  ldpair(jh, cur0, cur1, cur2, cur3);

  #pragma unroll 1
  for (int pp = 0; pp < 25; pp++) {
    const int p = 2*pp + jh;
    const int pn = (pp < 24) ? (p + 2) : p;
    ldpair(pn, nx0, nx1, nx2, nx3);
    const int jt0 = 2*p;
    float4 bb0 = *(const float4*)&b2s[jt0*16 + rg*4];
    float4 bb1 = *(const float4*)&b2s[(jt0+1)*16 + rg*4];
    floatx4 acc0[4], acc1[4];
    #pragma unroll
    for (int nt = 0; nt < 4; nt++) {
      floatx4 c0 = {bb0.x, bb0.y, bb0.z, bb0.w};
      c0 = __builtin_amdgcn_mfma_f32_16x16x32_bf16(cur0, bfrag[nt][0], c0, 0, 0, 0);
      c0 = __builtin_amdgcn_mfma_f32_16x16x32_bf16(cur1, bfrag[nt][1], c0, 0, 0, 0);
      acc0[nt] = c0;
      floatx4 c1 = {bb1.x, bb1.y, bb1.z, bb1.w};
      c1 = __builtin_amdgcn_mfma_f32_16x16x32_bf16(cur2, bfrag[nt][0], c1, 0, 0, 0);
      c1 = __builtin_amdgcn_mfma_f32_16x16x32_bf16(cur3, bfrag[nt][1], c1, 0, 0, 0);
      acc1[nt] = c1;
    }
    if (p < 32) {                      // w1: u = p, both tiles share cf
      #pragma unroll
      for (int nt = 0; nt < 4; nt++) {
        float cf = Wt[p*64 + nt*16 + col] * sh0c[nt];
        #pragma unroll
        for (int r = 0; r < 4; r++) {
          sacc[nt][r]   = fmaf(cf, acc0[nt][r], sacc[nt][r]);
          sacc[nt][4+r] = fmaf(cf, acc1[nt][r], sacc[nt][4+r]);
        }
      }
    } else if (p < 34) {               // w2: coef = v[u][c]*sh0
      const int u0 = (jt0 - 64)*2 + rgh, u1 = u0 + 2;
      #pragma unroll
      for (int nt = 0; nt < 4; nt++) {
        #pragma unroll
        for (int c3 = 0; c3 < 3; c3++) {
          float cf0 = Wt[(32 + u0*3 + c3)*64 + nt*16 + col] * sh0c[nt];
          float cf1 = Wt[(32 + u1*3 + c3)*64 + nt*16 + col] * sh0c[nt];
          #pragma unroll
          for (int r = 0; r < 4; r++) {
            vacc[nt][c3*4+r] = fmaf(cf0, acc0[nt][r], vacc[nt][c3*4+r]);
            vacc[nt][c3*4+r] = fmaf(cf1, acc1[nt][r], vacc[nt][c3*4+r]);
          }
        }
      }
    } else if (p < 42) {               // w3: coef = s[u]*sh1[c]
      const int u0 = (jt0 - 68)*2 + rgh, u1 = u0 + 2;
      #pragma unroll
      for (int nt = 0; nt < 4; nt++) {
        float sv0 = Wt[u0*64 + nt*16 + col];
        float sv1 = Wt[u1*64 + nt*16 + col];
        #pragma unroll
        for (int c3 = 0; c3 < 3; c3++) {
          float cf0 = sv0 * sh1c[nt][c3];
          float cf1 = sv1 * sh1c[nt][c3];
          #pragma unroll
          for (int r = 0; r < 4; r++) {
            vacc[nt][c3*4+r] = fmaf(cf0, acc0[nt][r], vacc[nt][c3*4+r]);
            vacc[nt][c3*4+r] = fmaf(cf1, acc1[nt][r], vacc[nt][c3*4+r]);
          }
        }
      }
    } else {                           // w4: u = p-42, coef = dot[u]
      const int u = p - 42;
      #pragma unroll
      for (int nt = 0; nt < 4; nt++) {
        float cf = Wt[(56 + u)*64 + nt*16 + col];
        #pragma unroll
        for (int r = 0; r < 4; r++) {
          sacc[nt][r]   = fmaf(cf, acc0[nt][r], sacc[nt][r]);
          sacc[nt][4+r] = fmaf(cf, acc1[nt][r], sacc[nt][4+r]);
        }
      }
    }
    cur0 = nx0; cur1 = nx1; cur2 = nx2; cur3 = nx3;
  }

  // ---- partial exchange: jh1 -> LDS, jh0 combines
  __syncthreads();
  if (jh == 1) {
    #pragma unroll
    for (int nt = 0; nt < 4; nt++)
      #pragma unroll
      for (int k = 0; k < 8; k++)
        Wt[(nt*8 + k)*64 + lane] = sacc[nt][k];
    #pragma unroll
    for (int nt = 0; nt < 4; nt++)
      #pragma unroll
      for (int k = 0; k < 12; k++) {
        float tot = vacc[nt][k] + __shfl_xor(vacc[nt][k], 32);
        if (rg < 2) Wt[2048 + (nt*12 + k)*32 + lane] = tot;
      }
  }
  __syncthreads();
  if (jh == 0) {
    const float ascale = 0.15811388300841897f;   // 1/sqrt(40)
    #pragma unroll
    for (int nt = 0; nt < 4; nt++)
      #pragma unroll
      for (int k = 0; k < 8; k++)
        sacc[nt][k] = (sacc[nt][k] + Wt[(nt*8 + k)*64 + lane]) * ascale;
    float vtot[4][12];
    #pragma unroll
    for (int nt = 0; nt < 4; nt++)
      #pragma unroll
      for (int k = 0; k < 12; k++) {
        float t0 = vacc[nt][k] + __shfl_xor(vacc[nt][k], 32);
        vtot[nt][k] = (t0 + Wt[2048 + (nt*12 + k)*32 + (lane & 31)]) * ascale;
      }
    // transpose into Wt with quad swizzle (q+el)&15; same-wave DS ordering is in-order
    #pragma unroll
    for (int nt = 0; nt < 4; nt++) {
      int el = nt*16 + col;
      #pragma unroll
      for (int pq = 0; pq < 2; pq++) {           // sacc quads q = pq*4+rg
        int q = pq*4 + rg;
        *(float4*)&Wt[el*64 + (((q + el) & 15) << 2)] = *(float4*)&sacc[nt][pq*4];
      }
      if (rg < 2) {                              // vector: 12 floats at idx 32+rg*12, quads 8+rg*3+j
        float tmp[12];
        #pragma unroll
        for (int c3 = 0; c3 < 3; c3++)
          #pragma unroll
          for (int r = 0; r < 4; r++) tmp[r*3 + c3] = vtot[nt][c3*4 + r];
        #pragma unroll
        for (int j = 0; j < 3; j++) {
          int q = 8 + rg*3 + j;
          *(float4*)&Wt[el*64 + (((q + el) & 15) << 2)] = *(float4*)&tmp[j*4];
        }
      }
    }
    #pragma unroll
    for (int it = 0; it < 14; it++) {
      int flat = it*64 + lane;                   // 64 rows x 14 quads
      int el = flat / 14, fq = flat - el*14;
      int e = e0 + el;
      if (e < NEDGES) {
        float4 val = *(const float4*)&Wt[el*64 + (((fq + el) & 15) << 2)];
        *(float4*)(tp + (size_t)pos_s[eg][el]*DNODE + fq*4) = val;
      }
    }
  }
}

// ---- per-node mean + residual + BN partials (contiguous CSR rows)
__global__ __launch_bounds__(256) void k_gather(const float* __restrict__ tp,
                                                const int* __restrict__ offs,
                                                const float* __restrict__ node_attr,
                                                float* __restrict__ pre,
                                                float* __restrict__ pstat) {
  __shared__ float redS[4*64], redQ[4*64];
  int t = threadIdx.x, wave = t >> 6, lane = t & 63;
  int gw = blockIdx.x * 4 + wave;
  const int W = 640 * 4;
  int off = (lane < DNODE) ? lane : 0;
  float ssum = 0.f, ssq = 0.f;
  for (int n = gw; n < NNODES; n += W) {
    int beg = offs[n], end = offs[n+1];
    float acc = 0.f;
    int i = beg;
    for (; i + 4 <= end; i += 4) {
      float v0 = tp[(size_t)(i+0)*DNODE + off];
      float v1 = tp[(size_t)(i+1)*DNODE + off];
      float v2 = tp[(size_t)(i+2)*DNODE + off];
      float v3 = tp[(size_t)(i+3)*DNODE + off];
      acc += (v0 + v1) + (v2 + v3);
    }
    for (; i < end; i++) acc += tp[(size_t)i*DNODE + off];
    int c = end - beg; if (c < 1) c = 1;
    float m = acc / (float)c + node_attr[(size_t)n*DNODE + off];
    if (lane < DNODE) { pre[(size_t)n*DNODE + lane] = m; ssum += m; ssq += m*m; }
  }
  redS[wave*64 + lane] = ssum;
  redQ[wave*64 + lane] = ssq;
  __syncthreads();
  if (wave == 0 && lane < DNODE) {
    float a = redS[lane] + redS[64+lane] + redS[128+lane] + redS[192+lane];
    float b = redQ[lane] + redQ[64+lane] + redQ[128+lane] + redQ[192+lane];
    pstat[(size_t)blockIdx.x*112 + lane] = a;
    pstat[(size_t)blockIdx.x*112 + 56 + lane] = b;
  }
}

// ---- reduce 640 partials -> stats[112]
__global__ __launch_bounds__(256) void k_stats(const float* __restrict__ pstat,
                                               float* __restrict__ stats) {
  int f = blockIdx.x * 4 + (threadIdx.x >> 6);
  int lane = threadIdx.x & 63;
  float v = 0.f;
  for (int b = lane; b < 640; b += 64) v += pstat[(size_t)b*112 + f];
  #pragma unroll
  for (int o = 32; o; o >>= 1) v += __shfl_xor(v, o);
  if (lane == 0) stats[f] = v;
}

// ---- batch norm -> d_out
__global__ __launch_bounds__(256) void k_norm(const float* __restrict__ pre,
                                              const float* __restrict__ stats,
                                              const float* __restrict__ gs,
                                              const float* __restrict__ bs,
                                              const float* __restrict__ gv,
                                              float* __restrict__ out) {
  int idx = blockIdx.x * 256 + threadIdx.x;
  if (idx >= NNODES * DNODE) return;
  int n = idx / DNODE;
  int d = idx - n * DNODE;
  float val = pre[idx];
  const float invN = 1.f / (float)NNODES;
  float res;
  if (d < 32) {
    float mu = stats[d] * invN;
    float var = stats[56 + d] * invN - mu * mu;
    res = (val - mu) * rsqrtf(var + 1e-4f) * gs[d] + bs[d];
  } else {
    int wi = (d - 32) / 3;
    float vn = (stats[56 + 32 + wi*3] + stats[56 + 32 + wi*3 + 1] +
                stats[56 + 32 + wi*3 + 2]) * (invN / 3.f);
    res = val * rsqrtf(vn + 1e-4f) * gv[wi];
  }
  out[idx] = res;
}

extern "C" void kernel_launch(void* const* d_in, const int* in_sizes, int n_in,
                              void* d_out, int out_size, void* d_ws, size_t ws_size,
                              hipStream_t stream) {
  const float* node_attr = (const float*)d_in[0];
  const int*   eidx      = (const int*)d_in[1];
  const float* edge_attr = (const float*)d_in[2];
  const float* edge_sh   = (const float*)d_in[3];
  const float* fc1w      = (const float*)d_in[4];
  const float* fc1b      = (const float*)d_in[5];
  const float* fc2w      = (const float*)d_in[6];
  const float* fc2b      = (const float*)d_in[7];
  const float* gs        = (const float*)d_in[8];
  const float* bs        = (const float*)d_in[9];
  const float* gv        = (const float*)d_in[10];

  float* ws = (float*)d_ws;
  float* tp    = ws;                                    // 5,600,000
  float* pre   = ws + 5600000;                          // 560,000
  float* stats = ws + 6160000;                          // 112 (pad to 128)
  float* pstat = ws + 6160128;                          // 640*112 = 71,680
  int*   cntn  = (int*)(ws + 6231808);                  // 10,000
  int*   offs  = (int*)(ws + 6241808);                  // 10,001 (pad 10,008)
  int*   cursor= (int*)(ws + 6251816);                  // 10,000
  int*   pos   = (int*)(ws + 6261816);                  // 100,000
  unsigned short* G  = (unsigned short*)(ws + 6361816); // 102,400 bf16 (16B aligned)
  unsigned short* hb = (unsigned short*)(ws + 6413016); // 6,400,000 bf16
  // total ~9.61M floats = 38.5 MB

  hipMemsetAsync(cntn, 0, (size_t)10000 * 4, stream);
  k_tr<<<400, 256, 0, stream>>>(fc2w, G);
  k_hidden<<<(NEDGES + 255) / 256, 256, 0, stream>>>(edge_attr, fc1w, fc1b, eidx, cntn, hb);
  k_scan<<<1, 1024, 0, stream>>>(cntn, offs, cursor);
  k_perm<<<(NEDGES + 255) / 256, 256, 0, stream>>>(eidx, cursor, pos);
  k_tp<<<782, 256, 0, stream>>>(hb, G, fc2b, eidx, node_attr, edge_sh, pos, tp);
  k_gather<<<640, 256, 0, stream>>>(tp, offs, node_attr, pre, pstat);
  k_stats<<<28, 256, 0, stream>>>(pstat, stats);
  k_norm<<<(NNODES * DNODE + 255) / 256, 256, 0, stream>>>(pre, stats, gs, bs, gv, (float*)d_out);
}